// Round 5
// baseline (1036.890 us; speedup 1.0000x reference)
//
#include <hip/hip_runtime.h>

// ---------------- types & helpers ----------------
typedef __attribute__((ext_vector_type(4))) float  f32x4;
typedef __attribute__((ext_vector_type(8))) short  s16x8;

__device__ __forceinline__ short f2bf(float f) {
    unsigned u = __builtin_bit_cast(unsigned, f);
    u += 0x7FFFu + ((u >> 16) & 1u);            // round-to-nearest-even
    return (short)(u >> 16);
}
__device__ __forceinline__ float bf2f(short s) {
    unsigned u = ((unsigned)(unsigned short)s) << 16;
    return __builtin_bit_cast(float, u);
}

#define DEPTH 128   // D == H*C == 128
#define HEADS 8
#define TILE_M 64
#define NPB 8       // nodes per block (one per wave)
#define ES_LD 132   // Es f32 row stride (132%32=4 -> bank hop)

// ---------------- kernel 0: W -> bf16, transposed (Wt[c][k]) ----------------
// order: 0=Wq 1=Wk 2=Wv 3=We 4=Wskip
__global__ void prep_w(const float* __restrict__ Wq, const float* __restrict__ Wk,
                       const float* __restrict__ Wv, const float* __restrict__ We,
                       const float* __restrict__ Wsk, short* __restrict__ Wt5) {
    int idx = blockIdx.x * 256 + threadIdx.x;
    if (idx >= 5 * DEPTH * DEPTH) return;
    int mat = idx >> 14;
    int rem = idx & 16383;
    int k = rem >> 7, c = rem & 127;
    const float* W = (mat == 0) ? Wq : (mat == 1) ? Wk : (mat == 2) ? Wv : (mat == 3) ? We : Wsk;
    Wt5[mat * 16384 + c * 128 + k] = f2bf(W[k * 128 + c]);
}

// ---------------- shared GEMM pieces ----------------
#define LOAD_BFRAG(bfrag, Wt, wc, lane)                                         \
    _Pragma("unroll") for (int nt_ = 0; nt_ < 4; nt_++)                         \
    _Pragma("unroll") for (int kk_ = 0; kk_ < 4; kk_++) {                       \
        int col_ = (wc) + nt_ * 16 + ((lane) & 15);                             \
        int kidx_ = kk_ * 32 + ((lane) >> 4) * 8;                               \
        bfrag[nt_][kk_] = *(const s16x8*)&(Wt)[col_ * 128 + kidx_];             \
    }

// ---------------- kernel 1: node projections (single pass, all 4 mats) ----------------
__global__ __launch_bounds__(512, 1) void node_proj(
    const float* __restrict__ x, const short* __restrict__ Wt5,
    const float* __restrict__ bq, const float* __restrict__ bk,
    const float* __restrict__ bv, const float* __restrict__ bsk,
    short* __restrict__ qb, short* __restrict__ kb, short* __restrict__ vb,
    float* __restrict__ skb, int Nn) {
    __shared__ short Asm[TILE_M][136];
    int tid = threadIdx.x, wave = tid >> 6, lane = tid & 63;
    int row0 = blockIdx.x * TILE_M;

    for (int i_ = 0; i_ < 4; i_++) {
        int f_ = tid + i_ * 512;
        int r_ = f_ >> 5, c4_ = f_ & 31;
        int gr_ = row0 + r_;
        float4 v_ = (gr_ < Nn) ? ((const float4*)x)[(size_t)gr_ * 32 + c4_]
                               : make_float4(0.f, 0.f, 0.f, 0.f);
        short* d_ = &Asm[r_][c4_ * 4];
        d_[0] = f2bf(v_.x); d_[1] = f2bf(v_.y); d_[2] = f2bf(v_.z); d_[3] = f2bf(v_.w);
    }
    __syncthreads();

    int wr = (wave >> 1) * 16, wc = (wave & 1) * 64;

    for (int mat = 0; mat < 4; mat++) {
        const short* Wt = Wt5 + ((mat < 3) ? mat : 4) * 16384;
        const float* bias = (mat == 0) ? bq : (mat == 1) ? bk : (mat == 2) ? bv : bsk;
        s16x8 bfrag[4][4];
        LOAD_BFRAG(bfrag, Wt, wc, lane);
        f32x4 acc[4];
#pragma unroll
        for (int nt = 0; nt < 4; nt++) acc[nt] = (f32x4){0.f, 0.f, 0.f, 0.f};
#pragma unroll
        for (int kk = 0; kk < 4; kk++) {
            s16x8 a = *(const s16x8*)&Asm[wr + (lane & 15)][kk * 32 + (lane >> 4) * 8];
#pragma unroll
            for (int nt = 0; nt < 4; nt++)
                acc[nt] = __builtin_amdgcn_mfma_f32_16x16x32_bf16(a, bfrag[nt][kk], acc[nt], 0, 0, 0);
        }
#pragma unroll
        for (int nt = 0; nt < 4; nt++) {
            int col = wc + nt * 16 + (lane & 15);
            float b = bias[col];
#pragma unroll
            for (int i = 0; i < 4; i++) {
                int row = row0 + wr + (lane >> 4) * 4 + i;
                if (row < Nn) {
                    float val = acc[nt][i] + b;
                    if (mat == 0)      qb[(size_t)row * 128 + col] = f2bf(val);
                    else if (mat == 1) kb[(size_t)row * 128 + col] = f2bf(val);
                    else if (mat == 2) vb[(size_t)row * 128 + col] = f2bf(val);
                    else               skb[(size_t)row * 128 + col] = val;
                }
            }
        }
    }
}

// ---------------- CSR build ----------------
__global__ void hist_dst(const int* __restrict__ eidx, int* __restrict__ cnt, int Ee) {
    int e = blockIdx.x * 256 + threadIdx.x;
    if (e < Ee) atomicAdd(&cnt[eidx[Ee + e]], 1);
}

__global__ __launch_bounds__(1024, 1) void scan_rowptr(const int* __restrict__ cnt,
                                                       int* __restrict__ rowptr, int Nn) {
    __shared__ int part[1024];
    int t = threadIdx.x;
    int chunk = (Nn + 1023) / 1024;
    int b = t * chunk;
    int e = b + chunk; if (e > Nn) e = Nn;
    int sum = 0;
    for (int i = b; i < e && i < Nn; i++) sum += cnt[i];
    part[t] = sum;
    __syncthreads();
    for (int off = 1; off < 1024; off <<= 1) {
        int v = (t >= off) ? part[t - off] : 0;
        __syncthreads();
        part[t] += v;
        __syncthreads();
    }
    int run = part[t] - sum;   // exclusive
    for (int i = b; i < e && i < Nn; i++) { rowptr[i] = run; run += cnt[i]; }
    if (t == 1023) rowptr[Nn] = part[1023];
}

__global__ void fill_perm(const int* __restrict__ eidx, const int* __restrict__ rowptr,
                          int* __restrict__ cursor, int* __restrict__ perm, int Ee) {
    int e = blockIdx.x * 256 + threadIdx.x;
    if (e >= Ee) return;
    int d = eidx[Ee + e];
    int pos = atomicAdd(&cursor[d], 1);
    perm[rowptr[d] + pos] = e;
}

// ---------------- kernel 2: FUSED, flash-style per-tile two-pass ----------------
// Block owns NPB consecutive dst nodes (wave w -> node n0+w). Per 64-edge tile:
//   stage ea (perm-gather) -> MFMA e=ea@We -> Es f32 LDS
//   alpha phase: 512 threads, one (edge,head) each -> Als[64][8]
//   stats phase: owner wave: tile-max per head, ONE rescale, p=exp in place
//   PV phase: owner wave, independent iterations (p from LDS, vb row coalesced)
__global__ __launch_bounds__(512) void fused_attn(
    const float* __restrict__ ea, const short* __restrict__ Wt5,
    const short* __restrict__ qb, const short* __restrict__ kb,
    const short* __restrict__ vb, const int* __restrict__ eidx,
    const int* __restrict__ perm, const int* __restrict__ rowptr,
    const float* __restrict__ skb, float* __restrict__ out, int Nn, int Ee) {
    const short* Wt = Wt5 + 3 * 16384;  // We

    __shared__ __align__(16) float smraw[TILE_M * ES_LD];  // 33792 B, unioned
    __shared__ float Als[TILE_M][HEADS];                   // 2 KB
    __shared__ int Ss[TILE_M], Ds[TILE_M];
    short (*Asm)[136] = (short (*)[136])smraw;             // 17.4 KB overlay
    float (*Es)[ES_LD] = (float (*)[ES_LD])smraw;

    int tid = threadIdx.x, wave = tid >> 6, lane = tid & 63;
    int n0 = blockIdx.x * NPB;
    int myNode = n0 + wave;
    int lastN = (n0 + NPB < Nn) ? n0 + NPB : Nn;
    int blkBeg = rowptr[n0];
    int blkEnd = rowptr[lastN];
    int myBeg = (myNode < Nn) ? rowptr[myNode] : 0;
    int myEnd = (myNode < Nn) ? rowptr[myNode + 1] : 0;

    int wr = (wave >> 1) * 16, wc = (wave & 1) * 64;
    int hh = lane >> 3, j = lane & 7;     // stats-phase role; hh == head of lane's 2 channels
    float m = -3.0e38f, s = 0.f, acc0 = 0.f, acc1 = 0.f;

    for (int t0 = blkBeg; t0 < blkEnd; t0 += TILE_M) {
        int cnt = blkEnd - t0; if (cnt > TILE_M) cnt = TILE_M;

        // ---- stage: src/dst ids + ea rows (perm-gathered, 512B granular) ----
        if (tid < TILE_M) {
            int pe = (tid < cnt) ? perm[t0 + tid] : 0;
            Ss[tid] = (tid < cnt) ? eidx[pe] : 0;
            Ds[tid] = (tid < cnt) ? eidx[Ee + pe] : 0;
        }
        for (int i_ = 0; i_ < 4; i_++) {
            int f_ = tid + i_ * 512;
            int r_ = f_ >> 5, c4_ = f_ & 31;
            float4 v_;
            if (r_ < cnt) {
                int pe = perm[t0 + r_];          // redundant across 32 lanes, L1-hot
                v_ = ((const float4*)ea)[(size_t)pe * 32 + c4_];
            } else v_ = make_float4(0.f, 0.f, 0.f, 0.f);
            short* d_ = &Asm[r_][c4_ * 4];
            d_[0] = f2bf(v_.x); d_[1] = f2bf(v_.y); d_[2] = f2bf(v_.z); d_[3] = f2bf(v_.w);
        }
        __syncthreads();

        // ---- MFMA1: e = ea_tile @ We ----
        s16x8 bfrag[4][4];
        LOAD_BFRAG(bfrag, Wt, wc, lane);        // L1-resident 32KB
        f32x4 acc[4];
#pragma unroll
        for (int nt = 0; nt < 4; nt++) acc[nt] = (f32x4){0.f, 0.f, 0.f, 0.f};
#pragma unroll
        for (int kk = 0; kk < 4; kk++) {
            s16x8 a = *(const s16x8*)&Asm[wr + (lane & 15)][kk * 32 + (lane >> 4) * 8];
#pragma unroll
            for (int nt = 0; nt < 4; nt++)
                acc[nt] = __builtin_amdgcn_mfma_f32_16x16x32_bf16(a, bfrag[nt][kk], acc[nt], 0, 0, 0);
        }
        __syncthreads();   // Asm dead; buffer becomes Es

        // ---- write Es f32 ----
#pragma unroll
        for (int nt = 0; nt < 4; nt++) {
            int col = wc + nt * 16 + (lane & 15);
#pragma unroll
            for (int i = 0; i < 4; i++)
                Es[wr + (lane >> 4) * 4 + i][col] = acc[nt][i];
        }
        __syncthreads();

        // ---- alpha phase: one (edge, head) per thread ----
        {
            int eL = tid >> 3, h = tid & 7;
            if (eL < cnt) {
                int src = Ss[eL], dst = Ds[eL];
                const short* qp = &qb[(size_t)dst * 128 + h * 16];
                const short* kp = &kb[(size_t)src * 128 + h * 16];
                s16x8 q0 = *(const s16x8*)qp, q1 = *(const s16x8*)(qp + 8);
                s16x8 k0 = *(const s16x8*)kp, k1 = *(const s16x8*)(kp + 8);
                const float* ep = &Es[eL][h * 16];
                float a_val = 0.f;
#pragma unroll
                for (int c = 0; c < 8; c++) {
                    a_val += bf2f(q0[c]) * (bf2f(k0[c]) + ep[c]);
                    a_val += bf2f(q1[c]) * (bf2f(k1[c]) + ep[8 + c]);
                }
                Als[eL][h] = a_val * 0.25f;     // 1/sqrt(C), C=16
            }
        }
        __syncthreads();

        // ---- stats phase (owner wave, per head): tile max, one rescale, p in place ----
        int lo = myBeg > t0 ? myBeg : t0;
        int hi = myEnd < t0 + cnt ? myEnd : t0 + cnt;
        if (lo < hi) {
            float mt = -3.0e38f;
            for (int i = lo + j; i < hi; i += 8) mt = fmaxf(mt, Als[i - t0][hh]);
            mt = fmaxf(mt, __shfl_xor(mt, 1));
            mt = fmaxf(mt, __shfl_xor(mt, 2));
            mt = fmaxf(mt, __shfl_xor(mt, 4));
            float mn = fmaxf(m, mt);
            float r = __expf(m - mn);
            float st = 0.f;
            for (int i = lo + j; i < hi; i += 8) {
                float p = __expf(Als[i - t0][hh] - mn);
                Als[i - t0][hh] = p;
                st += p;
            }
            st += __shfl_xor(st, 1);
            st += __shfl_xor(st, 2);
            st += __shfl_xor(st, 4);
            s = s * r + st;
            m = mn;
            acc0 *= r; acc1 *= r;

            // ---- PV phase: independent iterations ----
            for (int i = lo; i < hi; i++) {
                int eL = i - t0;
                int src = Ss[eL];
                float p = Als[eL][hh];                                  // LDS broadcast
                unsigned vv = *(const unsigned*)&vb[(size_t)src * 128 + lane * 2];
                float2 e2 = *(const float2*)&Es[eL][lane * 2];
                acc0 += p * (bf2f((short)(vv & 0xffff)) + e2.x);
                acc1 += p * (bf2f((short)(vv >> 16))    + e2.y);
            }
        }
        __syncthreads();   // protect Es/Als/Ss before next tile's staging
    }

    // ---- epilogue: out = acc/(s+eps) + skip ----
    if (myNode < Nn) {
        float inv = 1.f / (s + 1e-16f);
        size_t o = (size_t)myNode * 128 + lane * 2;
        float2 sk = *(const float2*)&skb[o];
        float2 res = make_float2(acc0 * inv + sk.x, acc1 * inv + sk.y);
        *(float2*)&out[o] = res;
    }
}

// ---------------- launch ----------------
extern "C" void kernel_launch(void* const* d_in, const int* in_sizes, int n_in,
                              void* d_out, int out_size, void* d_ws, size_t ws_size,
                              hipStream_t stream) {
    const float* x   = (const float*)d_in[0];
    const float* ea  = (const float*)d_in[1];
    const float* Wq  = (const float*)d_in[2];
    const float* bq  = (const float*)d_in[3];
    const float* Wk  = (const float*)d_in[4];
    const float* bk  = (const float*)d_in[5];
    const float* Wv  = (const float*)d_in[6];
    const float* bv  = (const float*)d_in[7];
    const float* We  = (const float*)d_in[8];
    const float* Wsk = (const float*)d_in[9];
    const float* bsk = (const float*)d_in[10];
    const int*   eidx = (const int*)d_in[11];

    int Nn = in_sizes[0] / 128;   // 50000
    int Ee = in_sizes[1] / 128;   // 800000
    float* out = (float*)d_out;

    // ws layout
    size_t need = 0;
    size_t off_qb  = need; need += (size_t)Nn * 128 * 2;   // qb bf16
    size_t off_kb  = need; need += (size_t)Nn * 128 * 2;   // kb bf16
    size_t off_vb  = need; need += (size_t)Nn * 128 * 2;   // vb bf16
    size_t off_skb = need; need += (size_t)Nn * 128 * 4;   // skip f32
    size_t off_perm= need; need += (size_t)Ee * 4;         // perm
    size_t off_rp  = need; need += (size_t)(Nn + 1) * 4;   // rowptr
    size_t off_cnt = need; need += (size_t)Nn * 4;         // counts
    size_t off_cur = need; need += (size_t)Nn * 4;         // cursors
    size_t off_wt  = need; need += 5 * 16384 * 2;          // Wt5
    (void)need;

    char* ws = (char*)d_ws;
    short* qb    = (short*)(ws + off_qb);
    short* kb    = (short*)(ws + off_kb);
    short* vb    = (short*)(ws + off_vb);
    float* skb   = (float*)(ws + off_skb);
    int*   perm  = (int*)(ws + off_perm);
    int*   rowptr= (int*)(ws + off_rp);
    int*   cnt   = (int*)(ws + off_cnt);
    int*   cursor= (int*)(ws + off_cur);
    short* Wt5   = (short*)(ws + off_wt);

    hipMemsetAsync(cnt, 0, (size_t)Nn * 4, stream);
    hipMemsetAsync(cursor, 0, (size_t)Nn * 4, stream);

    prep_w<<<(5 * 16384 + 255) / 256, 256, 0, stream>>>(Wq, Wk, Wv, We, Wsk, Wt5);
    hist_dst<<<(Ee + 255) / 256, 256, 0, stream>>>(eidx, cnt, Ee);
    scan_rowptr<<<1, 1024, 0, stream>>>(cnt, rowptr, Nn);
    fill_perm<<<(Ee + 255) / 256, 256, 0, stream>>>(eidx, rowptr, cursor, perm, Ee);
    node_proj<<<(Nn + TILE_M - 1) / TILE_M, 512, 0, stream>>>(
        x, Wt5, bq, bk, bv, bsk, qb, kb, vb, skb, Nn);
    fused_attn<<<(Nn + NPB - 1) / NPB, 512, 0, stream>>>(
        ea, Wt5, qb, kb, vb, eidx, perm, rowptr, skb, out, Nn, Ee);
}

// Round 6
// 587.037 us; speedup vs baseline: 1.7663x; 1.7663x over previous
//
#include <hip/hip_runtime.h>

// ---------------- types & helpers ----------------
typedef __attribute__((ext_vector_type(4))) float  f32x4;
typedef __attribute__((ext_vector_type(8))) short  s16x8;

__device__ __forceinline__ short f2bf(float f) {
    unsigned u = __builtin_bit_cast(unsigned, f);
    u += 0x7FFFu + ((u >> 16) & 1u);            // round-to-nearest-even
    return (short)(u >> 16);
}
__device__ __forceinline__ float bf2f(short s) {
    unsigned u = ((unsigned)(unsigned short)s) << 16;
    return __builtin_bit_cast(float, u);
}

#define DEPTH 128   // D == H*C == 128
#define HEADS 8
#define TILE_M 64

// ---------------- kernel 0: W -> bf16, transposed (Wt[c][k]) ----------------
// order: 0=Wq 1=Wk 2=Wv 3=We 4=Wskip
__global__ void prep_w(const float* __restrict__ Wq, const float* __restrict__ Wk,
                       const float* __restrict__ Wv, const float* __restrict__ We,
                       const float* __restrict__ Wsk, short* __restrict__ Wt5) {
    int idx = blockIdx.x * 256 + threadIdx.x;
    if (idx >= 5 * DEPTH * DEPTH) return;
    int mat = idx >> 14;
    int rem = idx & 16383;
    int k = rem >> 7, c = rem & 127;
    const float* W = (mat == 0) ? Wq : (mat == 1) ? Wk : (mat == 2) ? Wv : (mat == 3) ? We : Wsk;
    Wt5[mat * 16384 + c * 128 + k] = f2bf(W[k * 128 + c]);
}

// ---------------- shared GEMM pieces ----------------
#define LOAD_BFRAG(bfrag, Wt, wc, lane)                                         \
    _Pragma("unroll") for (int nt_ = 0; nt_ < 4; nt_++)                         \
    _Pragma("unroll") for (int kk_ = 0; kk_ < 4; kk_++) {                       \
        int col_ = (wc) + nt_ * 16 + ((lane) & 15);                             \
        int kidx_ = kk_ * 32 + ((lane) >> 4) * 8;                               \
        bfrag[nt_][kk_] = *(const s16x8*)&(Wt)[col_ * 128 + kidx_];             \
    }

// ---------------- kernel 1: node projections (single pass, all 4 mats) ----------------
__global__ __launch_bounds__(512, 1) void node_proj(
    const float* __restrict__ x, const short* __restrict__ Wt5,
    const float* __restrict__ bq, const float* __restrict__ bk,
    const float* __restrict__ bv, const float* __restrict__ bsk,
    short* __restrict__ qb, short* __restrict__ kb, short* __restrict__ vb,
    float* __restrict__ skb, int Nn) {
    __shared__ short Asm[TILE_M][136];
    int tid = threadIdx.x, wave = tid >> 6, lane = tid & 63;
    int row0 = blockIdx.x * TILE_M;

    for (int i_ = 0; i_ < 4; i_++) {
        int f_ = tid + i_ * 512;
        int r_ = f_ >> 5, c4_ = f_ & 31;
        int gr_ = row0 + r_;
        float4 v_ = (gr_ < Nn) ? ((const float4*)x)[(size_t)gr_ * 32 + c4_]
                               : make_float4(0.f, 0.f, 0.f, 0.f);
        short* d_ = &Asm[r_][c4_ * 4];
        d_[0] = f2bf(v_.x); d_[1] = f2bf(v_.y); d_[2] = f2bf(v_.z); d_[3] = f2bf(v_.w);
    }
    __syncthreads();

    int wr = (wave >> 1) * 16, wc = (wave & 1) * 64;

    for (int mat = 0; mat < 4; mat++) {
        const short* Wt = Wt5 + ((mat < 3) ? mat : 4) * 16384;
        const float* bias = (mat == 0) ? bq : (mat == 1) ? bk : (mat == 2) ? bv : bsk;
        s16x8 bfrag[4][4];
        LOAD_BFRAG(bfrag, Wt, wc, lane);
        f32x4 acc[4];
#pragma unroll
        for (int nt = 0; nt < 4; nt++) acc[nt] = (f32x4){0.f, 0.f, 0.f, 0.f};
#pragma unroll
        for (int kk = 0; kk < 4; kk++) {
            s16x8 a = *(const s16x8*)&Asm[wr + (lane & 15)][kk * 32 + (lane >> 4) * 8];
#pragma unroll
            for (int nt = 0; nt < 4; nt++)
                acc[nt] = __builtin_amdgcn_mfma_f32_16x16x32_bf16(a, bfrag[nt][kk], acc[nt], 0, 0, 0);
        }
#pragma unroll
        for (int nt = 0; nt < 4; nt++) {
            int col = wc + nt * 16 + (lane & 15);
            float b = bias[col];
#pragma unroll
            for (int i = 0; i < 4; i++) {
                int row = row0 + wr + (lane >> 4) * 4 + i;
                if (row < Nn) {
                    float val = acc[nt][i] + b;
                    if (mat == 0)      qb[(size_t)row * 128 + col] = f2bf(val);
                    else if (mat == 1) kb[(size_t)row * 128 + col] = f2bf(val);
                    else if (mat == 2) vb[(size_t)row * 128 + col] = f2bf(val);
                    else               skb[(size_t)row * 128 + col] = val;
                }
            }
        }
    }
}

// ---------------- CSR build ----------------
__global__ void hist_dst(const int* __restrict__ eidx, int* __restrict__ cnt, int Ee) {
    int e = blockIdx.x * 256 + threadIdx.x;
    if (e < Ee) atomicAdd(&cnt[eidx[Ee + e]], 1);
}

__global__ __launch_bounds__(1024, 1) void scan_rowptr(const int* __restrict__ cnt,
                                                       int* __restrict__ rowptr, int Nn) {
    __shared__ int part[1024];
    int t = threadIdx.x;
    int chunk = (Nn + 1023) / 1024;
    int b = t * chunk;
    int e = b + chunk; if (e > Nn) e = Nn;
    int sum = 0;
    for (int i = b; i < e && i < Nn; i++) sum += cnt[i];
    part[t] = sum;
    __syncthreads();
    for (int off = 1; off < 1024; off <<= 1) {
        int v = (t >= off) ? part[t - off] : 0;
        __syncthreads();
        part[t] += v;
        __syncthreads();
    }
    int run = part[t] - sum;   // exclusive
    for (int i = b; i < e && i < Nn; i++) { rowptr[i] = run; run += cnt[i]; }
    if (t == 1023) rowptr[Nn] = part[1023];
}

// writes perm + srcs/dsts materialized in perm (dst-sorted) order
__global__ void fill_perm2(const int* __restrict__ eidx, const int* __restrict__ rowptr,
                           int* __restrict__ cursor, int* __restrict__ perm,
                           int* __restrict__ srcs, int* __restrict__ dsts, int Ee) {
    int e = blockIdx.x * 256 + threadIdx.x;
    if (e >= Ee) return;
    int s = eidx[e];
    int d = eidx[Ee + e];
    int pos = atomicAdd(&cursor[d], 1);
    int i = rowptr[d] + pos;
    perm[i] = e; srcs[i] = s; dsts[i] = d;
}

// ---------------- kernel 2: per-tile edge kernel, NO softmax-max pass ----------------
// One independent 64-edge tile (perm/dst-sorted) per block:
//   stage ea (perm-gather, 512B rows) -> MFMA e=ea@We -> Es bf16
//   alpha: 512 threads, one (edge,head) each; p = exp(min(alpha,60)) -> Pls
//   PV: wave = 8-edge group, lane = channel pair; independent iterations;
//       register segment-accumulate, atomicAdd flush at dst boundaries.
__global__ __launch_bounds__(512) void fused_edge(
    const float* __restrict__ ea, const short* __restrict__ Wt5,
    const short* __restrict__ qb, const short* __restrict__ kb,
    const short* __restrict__ vb,
    const int* __restrict__ perm, const int* __restrict__ srcs,
    const int* __restrict__ dsts,
    float* __restrict__ outacc, float* __restrict__ denom, int Ee) {
    const short* Wt = Wt5 + 3 * 16384;  // We

    __shared__ short Asm[TILE_M][136];      // 17.4 KB
    __shared__ short Es[TILE_M][136];       // 17.4 KB
    __shared__ float Pls[TILE_M][HEADS];    // 2 KB
    __shared__ int Ss[TILE_M], Ds[TILE_M];

    int tid = threadIdx.x, wave = tid >> 6, lane = tid & 63;
    int e0 = blockIdx.x * TILE_M;
    int cnt = Ee - e0; if (cnt > TILE_M) cnt = TILE_M;

    // ---- phase 0: stage ids + ea rows ----
    if (tid < TILE_M) {
        Ss[tid] = (tid < cnt) ? srcs[e0 + tid] : 0;
        Ds[tid] = (tid < cnt) ? dsts[e0 + tid] : -1;
    }
    for (int i_ = 0; i_ < 4; i_++) {
        int f_ = tid + i_ * 512;
        int r_ = f_ >> 5, c4_ = f_ & 31;
        float4 v_;
        if (r_ < cnt) {
            int pe = perm[e0 + r_];          // redundant across 32 lanes, L1-hot
            v_ = ((const float4*)ea)[(size_t)pe * 32 + c4_];
        } else v_ = make_float4(0.f, 0.f, 0.f, 0.f);
        short* d_ = &Asm[r_][c4_ * 4];
        d_[0] = f2bf(v_.x); d_[1] = f2bf(v_.y); d_[2] = f2bf(v_.z); d_[3] = f2bf(v_.w);
    }
    __syncthreads();

    // ---- phase 1: MFMA e = ea_tile @ We -> Es (bf16) ----
    int wr = (wave >> 1) * 16, wc = (wave & 1) * 64;
    {
        s16x8 bfrag[4][4];
        LOAD_BFRAG(bfrag, Wt, wc, lane);    // L1-resident 32KB
        f32x4 acc[4];
#pragma unroll
        for (int nt = 0; nt < 4; nt++) acc[nt] = (f32x4){0.f, 0.f, 0.f, 0.f};
#pragma unroll
        for (int kk = 0; kk < 4; kk++) {
            s16x8 a = *(const s16x8*)&Asm[wr + (lane & 15)][kk * 32 + (lane >> 4) * 8];
#pragma unroll
            for (int nt = 0; nt < 4; nt++)
                acc[nt] = __builtin_amdgcn_mfma_f32_16x16x32_bf16(a, bfrag[nt][kk], acc[nt], 0, 0, 0);
        }
#pragma unroll
        for (int nt = 0; nt < 4; nt++) {
            int col = wc + nt * 16 + (lane & 15);
#pragma unroll
            for (int i = 0; i < 4; i++)
                Es[wr + (lane >> 4) * 4 + i][col] = f2bf(acc[nt][i]);
        }
    }
    __syncthreads();

    // ---- phase 2: alpha + exp (one (edge,head) per thread; no reductions) ----
    {
        int eL = tid >> 3, h = tid & 7;
        if (eL < cnt) {
            int src = Ss[eL], dst = Ds[eL];
            const short* qp = &qb[(size_t)dst * 128 + h * 16];
            const short* kp = &kb[(size_t)src * 128 + h * 16];
            s16x8 q0 = *(const s16x8*)qp, q1 = *(const s16x8*)(qp + 8);
            s16x8 k0 = *(const s16x8*)kp, k1 = *(const s16x8*)(kp + 8);
            s16x8 ev0 = *(const s16x8*)&Es[eL][h * 16];
            s16x8 ev1 = *(const s16x8*)&Es[eL][h * 16 + 8];
            float a_val = 0.f;
#pragma unroll
            for (int c = 0; c < 8; c++) {
                a_val += bf2f(q0[c]) * (bf2f(k0[c]) + bf2f(ev0[c]));
                a_val += bf2f(q1[c]) * (bf2f(k1[c]) + bf2f(ev1[c]));
            }
            a_val *= 0.25f;                  // 1/sqrt(C), C=16
            // exp WITHOUT per-node max: cancels in p/sum(p); clamp for inf-safety
            Pls[eL][h] = __expf(fminf(a_val, 60.f));
        }
    }
    __syncthreads();

    // ---- phase 3: PV, independent iterations + segment-aggregated atomics ----
    {
        int eg = wave;          // 8-edge group
        int cp = lane;          // channel pair: channels 2cp, 2cp+1
        int base = eg * 8;
        int h = cp >> 3;
        float c0 = 0.f, c1 = 0.f, pd = 0.f;
        int curd = (base < cnt) ? Ds[base] : -1;
#pragma unroll
        for (int k = 0; k < 8; k++) {
            int eL = base + k;
            if (eL >= cnt) break;
            int d = Ds[eL];
            if (d != curd) {                 // wave-uniform branch
                atomicAdd(&outacc[(size_t)curd * 128 + cp * 2],     c0);
                atomicAdd(&outacc[(size_t)curd * 128 + cp * 2 + 1], c1);
                if ((cp & 7) == 0) atomicAdd(&denom[(size_t)curd * HEADS + h], pd);
                c0 = c1 = pd = 0.f;
                curd = d;
            }
            float p = Pls[eL][h];                                   // LDS broadcast
            int src = Ss[eL];
            unsigned vv = *(const unsigned*)&vb[(size_t)src * 128 + cp * 2];
            unsigned ee = *(const unsigned*)&Es[eL][cp * 2];
            c0 += p * (bf2f((short)(vv & 0xffff)) + bf2f((short)(ee & 0xffff)));
            c1 += p * (bf2f((short)(vv >> 16))    + bf2f((short)(ee >> 16)));
            if ((cp & 7) == 0) pd += p;
        }
        if (curd >= 0) {
            atomicAdd(&outacc[(size_t)curd * 128 + cp * 2],     c0);
            atomicAdd(&outacc[(size_t)curd * 128 + cp * 2 + 1], c1);
            if ((cp & 7) == 0) atomicAdd(&denom[(size_t)curd * HEADS + h], pd);
        }
    }
}

// ---------------- kernel 3: finalize out = outacc/(denom+eps) + skip ----------------
__global__ void finalize(const float* __restrict__ outacc, const float* __restrict__ denom,
                         const float* __restrict__ skb, float* __restrict__ out, int total4) {
    int idx = blockIdx.x * 256 + threadIdx.x;
    if (idx >= total4) return;                 // total4 = N*32 (float4 units)
    int n = idx >> 5, q4 = idx & 31;           // 4 channels per thread
    int h = q4 >> 2;                           // head = (4*q4)/16
    float inv = 1.f / (denom[(size_t)n * HEADS + h] + 1e-16f);
    float4 a = ((const float4*)outacc)[idx];
    float4 sk = ((const float4*)skb)[idx];
    float4 r = make_float4(a.x * inv + sk.x, a.y * inv + sk.y,
                           a.z * inv + sk.z, a.w * inv + sk.w);
    ((float4*)out)[idx] = r;
}

// ---------------- launch ----------------
extern "C" void kernel_launch(void* const* d_in, const int* in_sizes, int n_in,
                              void* d_out, int out_size, void* d_ws, size_t ws_size,
                              hipStream_t stream) {
    const float* x   = (const float*)d_in[0];
    const float* ea  = (const float*)d_in[1];
    const float* Wq  = (const float*)d_in[2];
    const float* bq  = (const float*)d_in[3];
    const float* Wk  = (const float*)d_in[4];
    const float* bk  = (const float*)d_in[5];
    const float* Wv  = (const float*)d_in[6];
    const float* bv  = (const float*)d_in[7];
    const float* We  = (const float*)d_in[8];
    const float* Wsk = (const float*)d_in[9];
    const float* bsk = (const float*)d_in[10];
    const int*   eidx = (const int*)d_in[11];

    int Nn = in_sizes[0] / 128;   // 50000
    int Ee = in_sizes[1] / 128;   // 800000
    float* out = (float*)d_out;

    // ws layout
    size_t need = 0;
    size_t off_qb  = need; need += (size_t)Nn * 128 * 2;   // qb bf16
    size_t off_kb  = need; need += (size_t)Nn * 128 * 2;   // kb bf16
    size_t off_vb  = need; need += (size_t)Nn * 128 * 2;   // vb bf16
    size_t off_skb = need; need += (size_t)Nn * 128 * 4;   // skip f32
    size_t off_oa  = need; need += (size_t)Nn * 128 * 4;   // outacc f32
    size_t off_dn  = need; need += (size_t)Nn * HEADS * 4; // denom f32
    size_t off_perm= need; need += (size_t)Ee * 4;         // perm
    size_t off_src = need; need += (size_t)Ee * 4;         // srcs (perm order)
    size_t off_dst = need; need += (size_t)Ee * 4;         // dsts (perm order)
    size_t off_rp  = need; need += (size_t)(Nn + 1) * 4;   // rowptr
    size_t off_cnt = need; need += (size_t)Nn * 4;         // counts
    size_t off_cur = need; need += (size_t)Nn * 4;         // cursors
    size_t off_wt  = need; need += 5 * 16384 * 2;          // Wt5
    (void)need;

    char* ws = (char*)d_ws;
    short* qb    = (short*)(ws + off_qb);
    short* kb    = (short*)(ws + off_kb);
    short* vb    = (short*)(ws + off_vb);
    float* skb   = (float*)(ws + off_skb);
    float* outacc= (float*)(ws + off_oa);
    float* denom = (float*)(ws + off_dn);
    int*   perm  = (int*)(ws + off_perm);
    int*   srcs  = (int*)(ws + off_src);
    int*   dsts  = (int*)(ws + off_dst);
    int*   rowptr= (int*)(ws + off_rp);
    int*   cnt   = (int*)(ws + off_cnt);
    int*   cursor= (int*)(ws + off_cur);
    short* Wt5   = (short*)(ws + off_wt);

    hipMemsetAsync(cnt, 0, (size_t)Nn * 4, stream);
    hipMemsetAsync(cursor, 0, (size_t)Nn * 4, stream);
    hipMemsetAsync(outacc, 0, (size_t)Nn * 128 * 4, stream);
    hipMemsetAsync(denom, 0, (size_t)Nn * HEADS * 4, stream);

    prep_w<<<(5 * 16384 + 255) / 256, 256, 0, stream>>>(Wq, Wk, Wv, We, Wsk, Wt5);
    hist_dst<<<(Ee + 255) / 256, 256, 0, stream>>>(eidx, cnt, Ee);
    scan_rowptr<<<1, 1024, 0, stream>>>(cnt, rowptr, Nn);
    fill_perm2<<<(Ee + 255) / 256, 256, 0, stream>>>(eidx, rowptr, cursor, perm, srcs, dsts, Ee);
    node_proj<<<(Nn + TILE_M - 1) / TILE_M, 512, 0, stream>>>(
        x, Wt5, bq, bk, bv, bsk, qb, kb, vb, skb, Nn);
    fused_edge<<<(Ee + TILE_M - 1) / TILE_M, 512, 0, stream>>>(
        ea, Wt5, qb, kb, vb, perm, srcs, dsts, outacc, denom, Ee);
    finalize<<<(Nn * 32 + 255) / 256, 256, 0, stream>>>(
        outacc, denom, skb, out, Nn * 32);
}